// Round 1
// baseline (773.102 us; speedup 1.0000x reference)
//
#include <hip/hip_runtime.h>
#include <math.h>

typedef unsigned short u16;
typedef unsigned int u32;
typedef __attribute__((ext_vector_type(8))) short bf16x8;
typedef __attribute__((ext_vector_type(4))) float f32x4;
typedef __attribute__((ext_vector_type(4))) u16 u16x4;

__device__ __forceinline__ u16 f2bf(float f) {
  u32 u = __builtin_bit_cast(u32, f);
  u32 r = (u + 0x7fffu + ((u >> 16) & 1u)) >> 16;
  return (u16)r;
}

__device__ __forceinline__ void async16(const void* g, void* l) {
  __builtin_amdgcn_global_load_lds(
      (__attribute__((address_space(1))) void*)(unsigned long long)(const char*)g,
      (__attribute__((address_space(3))) void*)l, 16, 0, 0);
}

// ---------------------------------------------------------------------------
// Weight f32 -> bf16 conversion (10 segments, one launch)
// ---------------------------------------------------------------------------
struct Conv10 {
  const float* src[10];
  u16* dst[10];
  int n[10];
};

__global__ __launch_bounds__(256) void convert10(Conv10 a) {
  const int seg = blockIdx.y;
  const long i = ((long)blockIdx.x * 256 + threadIdx.x) * 4;
  if (i >= a.n[seg]) return;
  float4 v = *(const float4*)&a.src[seg][i];
  u16x4 o;
  o.x = f2bf(v.x); o.y = f2bf(v.y); o.z = f2bf(v.z); o.w = f2bf(v.w);
  *(u16x4*)&a.dst[seg][i] = o;
}

// ---------------------------------------------------------------------------
// LayerNorm (two tensors fused in one launch), f32 in -> bf16 out, 1 wave/row
// ---------------------------------------------------------------------------
__global__ __launch_bounds__(256) void ln_dual(
    const float* __restrict__ in1, const float* __restrict__ g1, const float* __restrict__ b1,
    u16* __restrict__ out1, int rows1,
    const float* __restrict__ in2, const float* __restrict__ g2, const float* __restrict__ b2,
    u16* __restrict__ out2)
{
  const int w = threadIdx.x >> 6;
  const int lane = threadIdx.x & 63;
  const int row = blockIdx.x * 4 + w;
  const float* in; const float* gg; const float* bb; u16* out;
  if (row < rows1) { in = in1 + (size_t)row * 768; gg = g1; bb = b1; out = out1 + (size_t)row * 768; }
  else { const int r2 = row - rows1; in = in2 + (size_t)r2 * 768; gg = g2; bb = b2; out = out2 + (size_t)r2 * 768; }

  float4 v0 = *(const float4*)&in[lane * 4];
  float4 v1 = *(const float4*)&in[lane * 4 + 256];
  float4 v2 = *(const float4*)&in[lane * 4 + 512];
  float s = v0.x + v0.y + v0.z + v0.w + v1.x + v1.y + v1.z + v1.w + v2.x + v2.y + v2.z + v2.w;
  float s2 = v0.x*v0.x + v0.y*v0.y + v0.z*v0.z + v0.w*v0.w
           + v1.x*v1.x + v1.y*v1.y + v1.z*v1.z + v1.w*v1.w
           + v2.x*v2.x + v2.y*v2.y + v2.z*v2.z + v2.w*v2.w;
#pragma unroll
  for (int m = 1; m <= 32; m <<= 1) { s += __shfl_xor(s, m); s2 += __shfl_xor(s2, m); }
  const float mean = s * (1.0f / 768.0f);
  const float var = s2 * (1.0f / 768.0f) - mean * mean;
  const float rs = rsqrtf(var + 1e-5f);

#define LNSTORE(V, OFFS) { \
    float4 gv = *(const float4*)&gg[lane * 4 + OFFS]; \
    float4 bv = *(const float4*)&bb[lane * 4 + OFFS]; \
    u16x4 o; \
    o.x = f2bf((V.x - mean) * rs * gv.x + bv.x); \
    o.y = f2bf((V.y - mean) * rs * gv.y + bv.y); \
    o.z = f2bf((V.z - mean) * rs * gv.z + bv.z); \
    o.w = f2bf((V.w - mean) * rs * gv.w + bv.w); \
    *(u16x4*)&out[lane * 4 + OFFS] = o; }
  LNSTORE(v0, 0)
  LNSTORE(v1, 256)
  LNSTORE(v2, 512)
#undef LNSTORE
}

// ---------------------------------------------------------------------------
// bf16 GEMM: C(MxN) = A(MxK) @ W(NxK)^T + bias, 128x128 tile, 4 waves.
// EPI 0: bf16 out; EPI 1: bf16 gelu(out); EPI 2: f32 out = acc+bias+res.
// LDS tiles [128][32] with XOR slot swizzle (slot ^= (row>>1)&3) applied on
// the pre-swizzled global source (linear global_load_lds dest) and on reads.
// ---------------------------------------------------------------------------
template<int EPI>
__global__ __launch_bounds__(256) void gemm_bt(
    const u16* __restrict__ A, const u16* __restrict__ W,
    const float* __restrict__ bias, const float* __restrict__ res,
    void* __restrict__ outp, int M, int N, int K)
{
  __shared__ __align__(16) u16 As[128 * 32];
  __shared__ __align__(16) u16 Bs[128 * 32];
  const int tid = threadIdx.x;
  const int lane = tid & 63;
  const int w = tid >> 6;
  const long row0 = (long)blockIdx.y * 128;
  const long col0 = (long)blockIdx.x * 128;

  const int lr0 = w * 32 + (lane >> 2);
  const int lr1 = lr0 + 16;
  const int sl = lane & 3;
  const int ss0 = sl ^ ((lr0 >> 1) & 3);
  const int ss1 = sl ^ ((lr1 >> 1) & 3);
  const u16* ga0 = A + (row0 + lr0) * (long)K + ss0 * 8;
  const u16* ga1 = A + (row0 + lr1) * (long)K + ss1 * 8;
  const u16* gb0 = W + (col0 + lr0) * (long)K + ss0 * 8;
  const u16* gb1 = W + (col0 + lr1) * (long)K + ss1 * 8;
  u16* la0 = &As[(w * 2 + 0) * 512];
  u16* la1 = &As[(w * 2 + 1) * 512];
  u16* lb0 = &Bs[(w * 2 + 0) * 512];
  u16* lb1 = &Bs[(w * 2 + 1) * 512];

  const int fr = lane & 15;
  const int g = lane >> 4;
  const int wr = (w >> 1) * 64;
  const int wc = (w & 1) * 64;

  f32x4 acc[4][4];
#pragma unroll
  for (int m = 0; m < 4; ++m)
#pragma unroll
    for (int n = 0; n < 4; ++n) acc[m][n] = (f32x4){0.f, 0.f, 0.f, 0.f};

  for (int k0 = 0; k0 < K; k0 += 32) {
    async16(ga0, la0); async16(ga1, la1);
    async16(gb0, lb0); async16(gb1, lb1);
    ga0 += 32; ga1 += 32; gb0 += 32; gb1 += 32;
    __syncthreads();
    bf16x8 af[4], bfr[4];
#pragma unroll
    for (int m = 0; m < 4; ++m) {
      const int r = wr + m * 16 + fr;
      af[m] = *(const bf16x8*)&As[r * 32 + ((g ^ ((r >> 1) & 3)) * 8)];
    }
#pragma unroll
    for (int n = 0; n < 4; ++n) {
      const int r = wc + n * 16 + fr;
      bfr[n] = *(const bf16x8*)&Bs[r * 32 + ((g ^ ((r >> 1) & 3)) * 8)];
    }
#pragma unroll
    for (int m = 0; m < 4; ++m)
#pragma unroll
      for (int n = 0; n < 4; ++n)
        acc[m][n] = __builtin_amdgcn_mfma_f32_16x16x32_bf16(af[m], bfr[n], acc[m][n], 0, 0, 0);
    __syncthreads();
  }

#pragma unroll
  for (int n = 0; n < 4; ++n) {
    const long col = col0 + wc + n * 16 + fr;
    const float bv = bias[col];
#pragma unroll
    for (int m = 0; m < 4; ++m) {
#pragma unroll
      for (int j = 0; j < 4; ++j) {
        const long row = row0 + wr + m * 16 + g * 4 + j;
        const long off = row * N + col;
        float v = acc[m][n][j] + bv;
        if constexpr (EPI == 0) {
          ((u16*)outp)[off] = f2bf(v);
        } else if constexpr (EPI == 1) {
          float ge = 0.5f * v * (1.0f + erff(v * 0.70710678118654752f));
          ((u16*)outp)[off] = f2bf(ge);
        } else {
          ((float*)outp)[off] = v + res[off];
        }
      }
    }
  }
}

// ---------------------------------------------------------------------------
// Relative position index (matches _rel_index in reference)
// ---------------------------------------------------------------------------
template<int LQ>
__device__ __forceinline__ int rel_index(int q, int k) {
  if constexpr (LQ == 64) {  // z queries (8x8 grid), x keys (16x16 grid)
    const int qh = q >> 3, qw = q & 7, kh = k >> 4, kw = k & 15;
    return (qh - kh + 15) * 23 + (qw - kw + 15);
  } else {                   // x queries (16x16), z keys (8x8)
    const int qh = q >> 4, qw = q & 15, kh = k >> 3, kw = k & 7;
    return (qh - kh + 7) * 23 + (qw - kw + 7);
  }
}

// ---------------------------------------------------------------------------
// Fused cross attention, one block per (head, batch). 256 threads, MFMA.
// Q: (B*LQ, 768) bf16 ; KV: (B*LK, 1536) bf16 (k at +0, v at +768 per row)
// O: (B*LQ, 768) bf16
// ---------------------------------------------------------------------------
template<int LQ, int LK>
__global__ __launch_bounds__(256) void attn_kernel(
    const u16* __restrict__ Q, const u16* __restrict__ KV,
    const float* __restrict__ rpb, u16* __restrict__ O)
{
  constexpr int MT = LQ / 64;    // 16-row m-tiles per wave
  constexpr int NT = LK / 16;    // 16-col n-tiles (keys)
  constexpr int KSPV = LK / 32;  // K-steps for PV

  __shared__ __align__(16) u16 Qs[LQ * 64];
  __shared__ __align__(16) u16 Ks[LK * 64];
  __shared__ __align__(16) u16 Vt[64 * LK];
  __shared__ __align__(16) u16 Ps[LQ * LK];
  __shared__ float bias_s[529];

  const int h = blockIdx.x;
  const int b = blockIdx.y;
  const int tid = threadIdx.x;
  const int lane = tid & 63;
  const int w = tid >> 6;

  for (int i = tid; i < 529; i += 256) bias_s[i] = rpb[i * 12 + h];

#pragma unroll
  for (int it = 0; it < LQ * 8 / 256; ++it) {
    const int s = it * 256 + tid;
    const int r = s >> 3, sl2 = s & 7;
    bf16x8 v = *(const bf16x8*)&Q[(size_t)(b * LQ + r) * 768 + h * 64 + sl2 * 8];
    *(bf16x8*)&Qs[r * 64 + ((sl2 ^ (r & 7)) * 8)] = v;
  }
#pragma unroll
  for (int it = 0; it < LK * 8 / 256; ++it) {
    const int s = it * 256 + tid;
    const int r = s >> 3, sl2 = s & 7;
    bf16x8 v = *(const bf16x8*)&KV[(size_t)(b * LK + r) * 1536 + h * 64 + sl2 * 8];
    *(bf16x8*)&Ks[r * 64 + ((sl2 ^ (r & 7)) * 8)] = v;
  }
#pragma unroll
  for (int it = 0; it < LK * 8 / 256; ++it) {
    const int s = it * 256 + tid;
    const int r = s >> 3, sl2 = s & 7;
    const int d0 = sl2 * 8;
    bf16x8 v = *(const bf16x8*)&KV[(size_t)(b * LK + r) * 1536 + 768 + h * 64 + d0];
#pragma unroll
    for (int j = 0; j < 8; ++j) {
      const int d = d0 + j;
      Vt[d * LK + (((r >> 3) ^ (d & 7)) * 8) + (r & 7)] = (u16)v[j];
    }
  }
  __syncthreads();

  const int fr = lane & 15;
  const int g = lane >> 4;
  const int qbase = w * MT * 16;

  f32x4 sacc[MT][NT];
#pragma unroll
  for (int mt = 0; mt < MT; ++mt)
#pragma unroll
    for (int nt = 0; nt < NT; ++nt) sacc[mt][nt] = (f32x4){0.f, 0.f, 0.f, 0.f};

#pragma unroll
  for (int mt = 0; mt < MT; ++mt) {
    const int qr = qbase + mt * 16 + fr;
    bf16x8 aq0 = *(const bf16x8*)&Qs[qr * 64 + (((0 + g) ^ (qr & 7)) * 8)];
    bf16x8 aq1 = *(const bf16x8*)&Qs[qr * 64 + (((4 + g) ^ (qr & 7)) * 8)];
#pragma unroll
    for (int nt = 0; nt < NT; ++nt) {
      const int kr = nt * 16 + fr;
      bf16x8 bk0 = *(const bf16x8*)&Ks[kr * 64 + (((0 + g) ^ (kr & 7)) * 8)];
      bf16x8 bk1 = *(const bf16x8*)&Ks[kr * 64 + (((4 + g) ^ (kr & 7)) * 8)];
      sacc[mt][nt] = __builtin_amdgcn_mfma_f32_16x16x32_bf16(aq0, bk0, sacc[mt][nt], 0, 0, 0);
      sacc[mt][nt] = __builtin_amdgcn_mfma_f32_16x16x32_bf16(aq1, bk1, sacc[mt][nt], 0, 0, 0);
    }
  }

  // scale + bias + softmax (rows live in 16-lane groups) + write P (bf16, swizzled)
#pragma unroll
  for (int mt = 0; mt < MT; ++mt) {
#pragma unroll
    for (int reg = 0; reg < 4; ++reg) {
      const int q = qbase + mt * 16 + g * 4 + reg;
      float mx = -3.0e38f;
#pragma unroll
      for (int nt = 0; nt < NT; ++nt) {
        const int k = nt * 16 + fr;
        float s = sacc[mt][nt][reg] * 0.125f + bias_s[rel_index<LQ>(q, k)];
        sacc[mt][nt][reg] = s;
        mx = fmaxf(mx, s);
      }
      mx = fmaxf(mx, __shfl_xor(mx, 1));
      mx = fmaxf(mx, __shfl_xor(mx, 2));
      mx = fmaxf(mx, __shfl_xor(mx, 4));
      mx = fmaxf(mx, __shfl_xor(mx, 8));
      float sum = 0.f;
#pragma unroll
      for (int nt = 0; nt < NT; ++nt) {
        float p = __expf(sacc[mt][nt][reg] - mx);
        sacc[mt][nt][reg] = p;
        sum += p;
      }
      sum += __shfl_xor(sum, 1);
      sum += __shfl_xor(sum, 2);
      sum += __shfl_xor(sum, 4);
      sum += __shfl_xor(sum, 8);
      const float inv = 1.0f / sum;
#pragma unroll
      for (int nt = 0; nt < NT; ++nt) {
        const int k = nt * 16 + fr;
        Ps[q * LK + (((k >> 3) ^ (q & 7)) * 8) + (k & 7)] = f2bf(sacc[mt][nt][reg] * inv);
      }
    }
  }
  __syncthreads();

  f32x4 oacc[MT][4];
#pragma unroll
  for (int mt = 0; mt < MT; ++mt)
#pragma unroll
    for (int n = 0; n < 4; ++n) oacc[mt][n] = (f32x4){0.f, 0.f, 0.f, 0.f};

#pragma unroll
  for (int mt = 0; mt < MT; ++mt) {
    const int pr = qbase + mt * 16 + fr;
#pragma unroll
    for (int ks = 0; ks < KSPV; ++ks) {
      bf16x8 ap = *(const bf16x8*)&Ps[pr * LK + (((ks * 4 + g) ^ (pr & 7)) * 8)];
#pragma unroll
      for (int n = 0; n < 4; ++n) {
        const int d = n * 16 + fr;
        bf16x8 bv = *(const bf16x8*)&Vt[d * LK + (((ks * 4 + g) ^ (d & 7)) * 8)];
        oacc[mt][n] = __builtin_amdgcn_mfma_f32_16x16x32_bf16(ap, bv, oacc[mt][n], 0, 0, 0);
      }
    }
  }

#pragma unroll
  for (int mt = 0; mt < MT; ++mt)
#pragma unroll
    for (int n = 0; n < 4; ++n)
#pragma unroll
      for (int reg = 0; reg < 4; ++reg) {
        const int q = qbase + mt * 16 + g * 4 + reg;
        const int d = n * 16 + fr;
        O[(size_t)(b * LQ + q) * 768 + h * 64 + d] = f2bf(oacc[mt][n][reg]);
      }
}

// ---------------------------------------------------------------------------
// Host launcher
// ---------------------------------------------------------------------------
extern "C" void kernel_launch(void* const* d_in, const int* in_sizes, int n_in,
                              void* d_out, int out_size, void* d_ws, size_t ws_size,
                              hipStream_t stream)
{
  const float* z      = (const float*)d_in[0];
  const float* x      = (const float*)d_in[1];
  const float* zln1g  = (const float*)d_in[2];
  const float* zln1b  = (const float*)d_in[3];
  const float* xln1g  = (const float*)d_in[4];
  const float* xln1b  = (const float*)d_in[5];
  const float* zx_qw  = (const float*)d_in[6];
  const float* zx_qb  = (const float*)d_in[7];
  const float* zx_kvw = (const float*)d_in[8];
  const float* zx_kvb = (const float*)d_in[9];
  const float* zx_pw  = (const float*)d_in[10];
  const float* zx_pb  = (const float*)d_in[11];
  const float* zx_rpb = (const float*)d_in[12];
  const float* xz_qw  = (const float*)d_in[13];
  const float* xz_qb  = (const float*)d_in[14];
  const float* xz_kvw = (const float*)d_in[15];
  const float* xz_kvb = (const float*)d_in[16];
  const float* xz_pw  = (const float*)d_in[17];
  const float* xz_pb  = (const float*)d_in[18];
  const float* xz_rpb = (const float*)d_in[19];
  const float* zln2g  = (const float*)d_in[20];
  const float* zln2b  = (const float*)d_in[21];
  const float* zfc1w  = (const float*)d_in[22];
  const float* zfc1b  = (const float*)d_in[23];
  const float* zfc2w  = (const float*)d_in[24];
  const float* zfc2b  = (const float*)d_in[25];
  const float* xln2g  = (const float*)d_in[26];
  const float* xln2b  = (const float*)d_in[27];
  const float* xfc1w  = (const float*)d_in[28];
  const float* xfc1b  = (const float*)d_in[29];
  const float* xfc2w  = (const float*)d_in[30];
  const float* xfc2b  = (const float*)d_in[31];

  float* out = (float*)d_out;
  float* z2 = out;                       // 4096 x 768 f32
  float* x2 = out + 3145728;             // 16384 x 768 f32

  char* ws = (char*)d_ws;
  size_t off = 0;
  auto take = [&](size_t bytes) {
    char* p = ws + off;
    off += (bytes + 255) & ~(size_t)255;
    return p;
  };
  u16* w_zx_q  = (u16*)take(589824 * 2);
  u16* w_zx_kv = (u16*)take(1179648 * 2);
  u16* w_zx_p  = (u16*)take(589824 * 2);
  u16* w_xz_q  = (u16*)take(589824 * 2);
  u16* w_xz_kv = (u16*)take(1179648 * 2);
  u16* w_xz_p  = (u16*)take(589824 * 2);
  u16* w_zfc1  = (u16*)take(2359296 * 2);
  u16* w_zfc2  = (u16*)take(2359296 * 2);
  u16* w_xfc1  = (u16*)take(2359296 * 2);
  u16* w_xfc2  = (u16*)take(2359296 * 2);
  u16* regA    = (u16*)take(31457280);   // zn|xn -> ao_z|ao_x -> z2n|x2n
  u16* regB    = (u16*)take(94371840);   // q_z|kv_x|q_x|kv_z -> h (MLP hidden)

  u16* zn   = regA;
  u16* xn   = regA + 3145728;
  u16* q_z  = regB;
  u16* kv_x = regB + 3145728;
  u16* q_x  = regB + 3145728 + 25165824;
  u16* kv_z = regB + 3145728 + 25165824 + 12582912;
  u16* ao_z = zn;
  u16* ao_x = xn;
  u16* z2n  = zn;
  u16* x2n  = xn;
  u16* h    = regB;

  // 1. weights -> bf16
  Conv10 c;
  c.src[0] = zx_qw;  c.dst[0] = w_zx_q;  c.n[0] = 589824;
  c.src[1] = zx_kvw; c.dst[1] = w_zx_kv; c.n[1] = 1179648;
  c.src[2] = zx_pw;  c.dst[2] = w_zx_p;  c.n[2] = 589824;
  c.src[3] = xz_qw;  c.dst[3] = w_xz_q;  c.n[3] = 589824;
  c.src[4] = xz_kvw; c.dst[4] = w_xz_kv; c.n[4] = 1179648;
  c.src[5] = xz_pw;  c.dst[5] = w_xz_p;  c.n[5] = 589824;
  c.src[6] = zfc1w;  c.dst[6] = w_zfc1;  c.n[6] = 2359296;
  c.src[7] = zfc2w;  c.dst[7] = w_zfc2;  c.n[7] = 2359296;
  c.src[8] = xfc1w;  c.dst[8] = w_xfc1;  c.n[8] = 2359296;
  c.src[9] = xfc2w;  c.dst[9] = w_xfc2;  c.n[9] = 2359296;
  convert10<<<dim3(2304, 10), 256, 0, stream>>>(c);

  // 2. LN1 (z -> zn, x -> xn), bf16 out
  ln_dual<<<5120, 256, 0, stream>>>(z, zln1g, zln1b, zn, 4096, x, xln1g, xln1b, xn);

  // 3. QKV projections (bf16 GEMMs)
  gemm_bt<0><<<dim3(6, 32), 256, 0, stream>>>(zn, w_zx_q, zx_qb, nullptr, q_z, 4096, 768, 768);
  gemm_bt<0><<<dim3(12, 128), 256, 0, stream>>>(xn, w_zx_kv, zx_kvb, nullptr, kv_x, 16384, 1536, 768);
  gemm_bt<0><<<dim3(6, 128), 256, 0, stream>>>(xn, w_xz_q, xz_qb, nullptr, q_x, 16384, 768, 768);
  gemm_bt<0><<<dim3(12, 32), 256, 0, stream>>>(zn, w_xz_kv, xz_kvb, nullptr, kv_z, 4096, 1536, 768);

  // 4. attention (per head x batch)
  attn_kernel<64, 256><<<dim3(12, 64), 256, 0, stream>>>(q_z, kv_x, zx_rpb, ao_z);
  attn_kernel<256, 64><<<dim3(12, 64), 256, 0, stream>>>(q_x, kv_z, xz_rpb, ao_x);

  // 5. output proj + residual -> z2/x2 (f32, in d_out)
  gemm_bt<2><<<dim3(6, 32), 256, 0, stream>>>(ao_z, w_zx_p, zx_pb, z, z2, 4096, 768, 768);
  gemm_bt<2><<<dim3(6, 128), 256, 0, stream>>>(ao_x, w_xz_p, xz_pb, x, x2, 16384, 768, 768);

  // 6. LN2 -> z2n/x2n bf16
  ln_dual<<<5120, 256, 0, stream>>>(z2, zln2g, zln2b, z2n, 4096, x2, xln2g, xln2b, x2n);

  // 7. MLPs (fc1+gelu -> h bf16; fc2 + residual in-place on d_out)
  gemm_bt<1><<<dim3(24, 32), 256, 0, stream>>>(z2n, w_zfc1, zfc1b, nullptr, h, 4096, 3072, 768);
  gemm_bt<2><<<dim3(6, 32), 256, 0, stream>>>(h, w_zfc2, zfc2b, z2, z2, 4096, 768, 3072);

  gemm_bt<1><<<dim3(24, 64), 256, 0, stream>>>(x2n, w_xfc1, xfc1b, nullptr, h, 8192, 3072, 768);
  gemm_bt<2><<<dim3(6, 64), 256, 0, stream>>>(h, w_xfc2, xfc2b, x2, x2, 8192, 768, 3072);

  gemm_bt<1><<<dim3(24, 64), 256, 0, stream>>>(x2n + (size_t)8192 * 768, w_xfc1, xfc1b, nullptr, h, 8192, 3072, 768);
  gemm_bt<2><<<dim3(6, 64), 256, 0, stream>>>(h, w_xfc2, xfc2b, x2 + (size_t)8192 * 768, x2 + (size_t)8192 * 768, 8192, 768, 3072);
}